// Round 10
// baseline (126.284 us; speedup 1.0000x reference)
//
#include <hip/hip_runtime.h>
#include <math.h>

// ---------------------------------------------------------------------------
// GAT node classifier: 2x GATConv(H=2, concat=False/head-mean) + Linear.
// FULLY FUSED: each graph (100 nodes) is independent -> ONE kernel, one
// block (512 thr) per graph runs gemm1+agg1+gemm2+agg2+cls entirely in LDS.
//   prep: bucket edges by graph (two-level LDS-histogram scatter);
//         W1T/W2T bf16 transposed weights.
//   fused phases (127.5 KB dynamic LDS, region-reused):
//     A: zero/stage (scnt mult. counters, W1T, x->bf16, Wc)
//     1: h1 = x@W1 MFMA -> sHT (bf16, transposed) + logits (LDS)
//     2: agg1: masked softmax (4-bit edge multiplicity) -> P1 -> P@hT MFMA
//        -> sB bf16 [+b1, relu]
//     3: h2 = sB@W2 MFMA -> sHT + logits
//     4: agg2 -> sOut f32 [+b2]
//     5: cls: preds = sOut@Wc + bc -> global
// Region reuse: R1 = W1T -> P2 ; R3 = sX -> P1 -> W2T -> sOut(f32).
// NaN audit: sHT fully zeroed (cols 112..135 stay 0 both layers); sX/sB rows
// 100..111 zeroed; P pad cols written 0 by softmax; unstored D-rows may be
// garbage but are guarded by d<NPG.
// ---------------------------------------------------------------------------

#define NPG 100    // nodes per graph (fixed by problem)
#define CAP 2560   // bucket capacity per graph (mean 1700, +21 sigma)
#define EPB 4096   // edges per bucket-build block

// LDS carve (bytes); total 127464 -> launch with 127488
#define OFF_R1    0        // 34816: W1T [128][136] bf16 -> P2 [112][136]
#define OFF_HT    34816    // 34816: sHT [128 chan][136 node] bf16
#define OFF_R3    69632    // 30464: sX/P1 [112][136] bf16 -> W2T [128][72] -> sOut [112][68] f32
#define OFF_SB    100096   // 16128: sB [112][72] bf16 (layer-1 out)
#define OFF_SCNT  116224   // 6400:  scnt [100][16] u32 (4-bit multiplicities)
#define OFF_SAS   122624   // 896:   sAs [224] f32
#define OFF_SAD   123520   // 896:   sAd [224] f32
#define OFF_SRZ   124416   // 448:   sRZ [112] f32
#define OFF_SWC   124864   // 2560:  sWc [640] f32
#define OFF_SBC   127424   // 40:    sbc [10] f32
#define SMEM_BYTES 127488

typedef __attribute__((ext_vector_type(8))) short bf16x8;
typedef __attribute__((ext_vector_type(4))) float f32x4;

__device__ __forceinline__ float lrelu(float x) { return x > 0.f ? x : 0.2f * x; }

__device__ __forceinline__ unsigned short f2bf(float f) {
    unsigned int u = __float_as_uint(f);
    return (unsigned short)((u + 0x7FFF + ((u >> 16) & 1)) >> 16);  // RNE
}

__global__ void zero_gcnt(int* gcnt, int g) {
    int i = threadIdx.x;
    if (i < g) gcnt[i] = 0;
}

// Two-level bucketing: per-block LDS histogram over graphs, one global
// atomicAdd per (block,graph), then scatter staged edges to reserved ranges.
__global__ __launch_bounds__(1024) void bucket2_kernel(const int* __restrict__ src,
                                                       const int* __restrict__ dst,
                                                       int* gcnt,
                                                       unsigned short* __restrict__ bucket,
                                                       int e) {
    __shared__ int hist[512];
    __shared__ int base[512];
    __shared__ unsigned int staged[EPB];
    int tid = threadIdx.x;
    int e0 = blockIdx.x * EPB;
    int cnt = min(EPB, e - e0);

    for (int i = tid; i < 512; i += 1024) hist[i] = 0;
    __syncthreads();

    for (int i = tid; i < cnt; i += 1024) {
        int d = dst[e0 + i];
        int s = src[e0 + i];
        int g = d / NPG;
        int dloc = d - g * NPG;
        int sloc = s - g * NPG;
        staged[i] = ((unsigned)g << 16) | ((unsigned)dloc << 8) | (unsigned)sloc;
        atomicAdd(&hist[g], 1);
    }
    __syncthreads();

    if (tid < 512) {
        int h = hist[tid];
        base[tid] = h ? atomicAdd(&gcnt[tid], h) : 0;
        hist[tid] = 0;   // reuse as local cursor
    }
    __syncthreads();

    for (int i = tid; i < cnt; i += 1024) {
        unsigned v = staged[i];
        int g = v >> 16;
        int pos = base[g] + atomicAdd(&hist[g], 1);
        if (pos < CAP)
            bucket[(size_t)g * CAP + pos] = (unsigned short)(v & 0xFFFFu);
    }
}

// W1 [128][128], W2 [64][128] f32 -> W1T [c][k=128], W2T [c][k=64] bf16
__global__ __launch_bounds__(256) void convert_w(const float* __restrict__ W1,
                                                 const float* __restrict__ W2,
                                                 unsigned short* __restrict__ W1T,
                                                 unsigned short* __restrict__ W2T) {
    int stride = gridDim.x * 256;
    for (int i = blockIdx.x * 256 + threadIdx.x; i < 128 * 128; i += stride) {
        int k = i >> 7, c = i & 127;
        W1T[c * 128 + k] = f2bf(W1[i]);
    }
    for (int i = blockIdx.x * 256 + threadIdx.x; i < 64 * 128; i += stride) {
        int k = i >> 7, c = i & 127;
        W2T[c * 64 + k] = f2bf(W2[i]);
    }
}

// GEMM phase: sA [rows][SA] bf16 (M=112 rows used) @ sW [128 cols][SW] bf16
// -> sHT [col*136 + row] bf16 + attention logits into sAs/sAd (LDS, 224 ea).
// Fragment pattern verified on-device (rounds 8/9):
//   a: sA[row16+(lane&15)][ks*32+(lane>>4)*8], b likewise from sW rows=cols,
//   D: col=lane&15, row=(lane>>4)*4+j.
template <int K, int SA, int SW>
__device__ __forceinline__ void gemm_block(const unsigned short* sA,
                                           const unsigned short* sW,
                                           const float* __restrict__ a_src,
                                           const float* __restrict__ a_dst,
                                           unsigned short* sHT,
                                           float* sAs, float* sAd,
                                           int lane, int wave) {
    if (wave >= 7) return;   // M = 112 = 7 stripes of 16
    int fr = lane & 15, fk = (lane >> 4) * 8;
    f32x4 acc[8];
#pragma unroll
    for (int t = 0; t < 8; ++t) acc[t] = (f32x4){0.f, 0.f, 0.f, 0.f};
#pragma unroll
    for (int ks = 0; ks < K / 32; ++ks) {
        bf16x8 a = *reinterpret_cast<const bf16x8*>(&sA[(wave * 16 + fr) * SA + ks * 32 + fk]);
#pragma unroll
        for (int t = 0; t < 8; ++t) {
            bf16x8 b = *reinterpret_cast<const bf16x8*>(&sW[(t * 16 + fr) * SW + ks * 32 + fk]);
            acc[t] = __builtin_amdgcn_mfma_f32_16x16x32_bf16(a, b, acc[t], 0, 0, 0);
        }
    }
    int rb = wave * 16 + (lane >> 4) * 4;
    float ps0[4] = {0, 0, 0, 0}, ps1[4] = {0, 0, 0, 0};
    float pd0[4] = {0, 0, 0, 0}, pd1[4] = {0, 0, 0, 0};
#pragma unroll
    for (int t = 0; t < 8; ++t) {
        int col = t * 16 + fr;
        float as_ = a_src[col], ad_ = a_dst[col];
#pragma unroll
        for (int j = 0; j < 4; ++j) {
            float v = acc[t][j];
            sHT[col * 136 + rb + j] = f2bf(v);
            if (t < 4) { ps0[j] += v * as_; pd0[j] += v * ad_; }
            else       { ps1[j] += v * as_; pd1[j] += v * ad_; }
        }
    }
#pragma unroll
    for (int off = 1; off <= 8; off <<= 1) {
#pragma unroll
        for (int j = 0; j < 4; ++j) {
            ps0[j] += __shfl_xor(ps0[j], off);
            ps1[j] += __shfl_xor(ps1[j], off);
            pd0[j] += __shfl_xor(pd0[j], off);
            pd1[j] += __shfl_xor(pd1[j], off);
        }
    }
    if (fr == 0) {
#pragma unroll
        for (int j = 0; j < 4; ++j) {
            int d = rb + j;   // up to 111; arrays sized 224
            sAs[d * 2 + 0] = ps0[j];
            sAs[d * 2 + 1] = ps1[j];
            sAd[d * 2 + 0] = pd0[j];
            sAd[d * 2 + 1] = pd1[j];
        }
    }
}

// Aggregation: per head {masked softmax with 4-bit multiplicity -> sP;
// barrier; MFMA P@hT, res += acc/z; barrier}. res untouched rows may be
// garbage (sRZ uninit >=100) but are never stored.
__device__ __forceinline__ void agg_heads(unsigned short* sP,
                                          const unsigned short* sHT,
                                          const unsigned* scnt,
                                          const float* sAs, const float* sAd,
                                          float* sRZ, f32x4 res[4],
                                          int lane, int wave) {
    for (int head = 0; head < 2; ++head) {
        for (int d = wave; d < NPG; d += 8) {
            float adh = sAd[d * 2 + head];
            int s2 = lane + 64;
            unsigned m1 = (scnt[d * 16 + (lane >> 3)] >> ((lane & 7) * 4)) & 15u;
            unsigned m2 = (s2 < NPG) ? ((scnt[d * 16 + (s2 >> 3)] >> ((s2 & 7) * 4)) & 15u) : 0u;
            int si2 = (s2 < NPG) ? s2 : 0;
            float e1 = m1 ? lrelu(sAs[lane * 2 + head] + adh) : -INFINITY;
            float e2 = m2 ? lrelu(sAs[si2 * 2 + head] + adh) : -INFINITY;
            float mx = fmaxf(e1, e2);
            for (int off = 32; off; off >>= 1) mx = fmaxf(mx, __shfl_xor(mx, off));
            float p1 = (float)m1 * __expf(e1 - mx);   // 0 * exp(-inf) = 0
            float p2 = (float)m2 * __expf(e2 - mx);
            float z = p1 + p2;
            for (int off = 32; off; off >>= 1) z += __shfl_xor(z, off);
            sP[d * 136 + lane] = f2bf(p1);
            sP[d * 136 + s2] = f2bf(p2);
            if (lane == 0) sRZ[d] = 1.f / z;
        }
        __syncthreads();
#pragma unroll
        for (int i = 0; i < 4; ++i) {
            int t = wave + 8 * i;
            if (t < 28) {
                int mt = t >> 2, nt = t & 3;
                int arow = mt * 16 + (lane & 15);
                int brow = head * 64 + nt * 16 + (lane & 15);
                int kofs = (lane >> 4) * 8;
                f32x4 acc = (f32x4){0.f, 0.f, 0.f, 0.f};
#pragma unroll
                for (int ks = 0; ks < 4; ++ks) {
                    bf16x8 a = *reinterpret_cast<const bf16x8*>(&sP[arow * 136 + ks * 32 + kofs]);
                    bf16x8 b = *reinterpret_cast<const bf16x8*>(&sHT[brow * 136 + ks * 32 + kofs]);
                    acc = __builtin_amdgcn_mfma_f32_16x16x32_bf16(a, b, acc, 0, 0, 0);
                }
                int dbase = mt * 16 + (lane >> 4) * 4;
#pragma unroll
                for (int r = 0; r < 4; ++r)
                    res[i][r] += acc[r] * sRZ[dbase + r];
            }
        }
        __syncthreads();
    }
}

// One block (512 thr = 8 waves) per graph: the whole network in LDS.
__global__ __launch_bounds__(512) void graph_fused(
    const float* __restrict__ x,
    const unsigned short* __restrict__ W1T,
    const unsigned short* __restrict__ W2T,
    const float* __restrict__ as1, const float* __restrict__ ad1,
    const float* __restrict__ b1,
    const float* __restrict__ as2, const float* __restrict__ ad2,
    const float* __restrict__ b2,
    const float* __restrict__ Wc, const float* __restrict__ bc,
    const int* __restrict__ gcnt, const unsigned short* __restrict__ bucket,
    float* __restrict__ preds) {
    extern __shared__ char smem[];
    unsigned short* R1   = (unsigned short*)(smem + OFF_R1);   // W1T -> P2
    unsigned short* sHT  = (unsigned short*)(smem + OFF_HT);
    unsigned short* R3u  = (unsigned short*)(smem + OFF_R3);   // sX -> P1 -> W2T
    float*          sOut = (float*)(smem + OFF_R3);            // -> out2 f32
    unsigned short* sB   = (unsigned short*)(smem + OFF_SB);
    unsigned*       scnt = (unsigned*)(smem + OFF_SCNT);
    float*          sAs  = (float*)(smem + OFF_SAS);
    float*          sAd  = (float*)(smem + OFF_SAD);
    float*          sRZ  = (float*)(smem + OFF_SRZ);
    float*          sWc  = (float*)(smem + OFF_SWC);
    float*          sbc  = (float*)(smem + OFF_SBC);

    int g = blockIdx.x, gbase = g * NPG, tid = threadIdx.x;
    int lane = tid & 63, wave = tid >> 6;
    int cnt = min(gcnt[g], CAP);
    float4 z4 = make_float4(0.f, 0.f, 0.f, 0.f);

    // ---- phase A: zero + stage ----
    for (int i = tid; i < 1600; i += 512) scnt[i] = 0;
    for (int i = tid; i < 2176; i += 512)                    // zero sHT (34816 B)
        *reinterpret_cast<float4*>((char*)sHT + i * 16) = z4;
    for (int i = tid; i < 128 * 16; i += 512) {              // W1T -> R1
        int c = i >> 4, kc = (i & 15) * 8;
        *reinterpret_cast<float4*>(&R1[c * 136 + kc]) =
            *reinterpret_cast<const float4*>(&W1T[c * 128 + kc]);
    }
    for (int i = tid; i < NPG * 16; i += 512) {              // x -> sX bf16
        int r = i >> 4, kc = (i & 15) * 8;
        const float* xp = &x[(size_t)(gbase + r) * 128 + kc];
        float4 v0 = *reinterpret_cast<const float4*>(xp);
        float4 v1 = *reinterpret_cast<const float4*>(xp + 4);
        unsigned short t8[8] = {f2bf(v0.x), f2bf(v0.y), f2bf(v0.z), f2bf(v0.w),
                                f2bf(v1.x), f2bf(v1.y), f2bf(v1.z), f2bf(v1.w)};
        *reinterpret_cast<float4*>(&R3u[r * 136 + kc]) = *reinterpret_cast<float4*>(t8);
    }
    for (int i = tid; i < 12 * 17; i += 512) {               // zero sX rows 100..111
        int r = 100 + i / 17, c = (i % 17) * 8;
        *reinterpret_cast<float4*>(&R3u[r * 136 + c]) = z4;
    }
    for (int i = tid; i < 12 * 9; i += 512) {                // zero sB rows 100..111
        int r = 100 + i / 9, c = (i % 9) * 8;
        *reinterpret_cast<float4*>(&sB[r * 72 + c]) = z4;
    }
    for (int i = tid; i < 640; i += 512) sWc[i] = Wc[i];
    if (tid < 10) sbc[tid] = bc[tid];
    __syncthreads();
    for (int i = tid; i < cnt; i += 512) {                   // edge multiplicities
        unsigned v = bucket[(size_t)g * CAP + i];
        atomicAdd(&scnt[(v >> 8) * 16 + ((v & 255) >> 3)], 1u << ((v & 7) * 4));
    }
    __syncthreads();

    // ---- layer 1: gemm + agg ----
    gemm_block<128, 136, 136>(R3u, R1, as1, ad1, sHT, sAs, sAd, lane, wave);
    __syncthreads();

    f32x4 res[4];
#pragma unroll
    for (int i = 0; i < 4; ++i) res[i] = (f32x4){0.f, 0.f, 0.f, 0.f};
    agg_heads(R3u, sHT, scnt, sAs, sAd, sRZ, res, lane, wave);   // P1 over sX

    // epilogue -> sB (bf16, +b1, relu); stage W2T over P1 (agg barrier passed)
    {
        int fr = lane & 15;
#pragma unroll
        for (int i = 0; i < 4; ++i) {
            int t = wave + 8 * i;
            if (t < 28) {
                int mt = t >> 2, nt = t & 3;
                int col = nt * 16 + fr;
                float bv = b1[col];
#pragma unroll
                for (int r = 0; r < 4; ++r) {
                    int d = mt * 16 + (lane >> 4) * 4 + r;
                    if (d < NPG)
                        sB[d * 72 + col] = f2bf(fmaxf(0.5f * res[i][r] + bv, 0.f));
                }
            }
        }
    }
    for (int i = tid; i < 128 * 8; i += 512) {               // W2T -> R3
        int c = i >> 3, kc = (i & 7) * 8;
        *reinterpret_cast<float4*>(&R3u[c * 72 + kc]) =
            *reinterpret_cast<const float4*>(&W2T[c * 64 + kc]);
    }
    __syncthreads();

    // ---- layer 2: gemm + agg ----
    gemm_block<64, 72, 72>(sB, R3u, as2, ad2, sHT, sAs, sAd, lane, wave);
    __syncthreads();

#pragma unroll
    for (int i = 0; i < 4; ++i) res[i] = (f32x4){0.f, 0.f, 0.f, 0.f};
    agg_heads(R1, sHT, scnt, sAs, sAd, sRZ, res, lane, wave);    // P2 over W1T

    // epilogue -> sOut (f32, +b2, no relu) over dead W2T
    {
        int fr = lane & 15;
#pragma unroll
        for (int i = 0; i < 4; ++i) {
            int t = wave + 8 * i;
            if (t < 28) {
                int mt = t >> 2, nt = t & 3;
                int col = nt * 16 + fr;
                float bv = b2[col];
#pragma unroll
                for (int r = 0; r < 4; ++r) {
                    int d = mt * 16 + (lane >> 4) * 4 + r;
                    if (d < NPG) sOut[d * 68 + col] = 0.5f * res[i][r] + bv;
                }
            }
        }
    }
    __syncthreads();

    // ---- classifier ----
    for (int idx = tid; idx < NPG * 10; idx += 512) {
        int d = idx / 10, j = idx % 10;
        float acc = sbc[j];
#pragma unroll 8
        for (int c = 0; c < 64; ++c) acc += sOut[d * 68 + c] * sWc[c * 10 + j];
        preds[(size_t)(gbase + d) * 10 + j] = acc;
    }
}

__global__ void ycopy_kernel(const int* __restrict__ y, float* __restrict__ out, int n) {
    int i = blockIdx.x * 256 + threadIdx.x;
    if (i < n) out[i] = (float)y[i];
}

extern "C" void kernel_launch(void* const* d_in, const int* in_sizes, int n_in,
                              void* d_out, int out_size, void* d_ws, size_t ws_size,
                              hipStream_t stream) {
    const float* x   = (const float*)d_in[0];
    const int*   ei  = (const int*)d_in[1];
    const int*   y   = (const int*)d_in[3];
    const float* W1  = (const float*)d_in[4];
    const float* as1 = (const float*)d_in[5];
    const float* ad1 = (const float*)d_in[6];
    const float* b1  = (const float*)d_in[7];
    const float* W2  = (const float*)d_in[8];
    const float* as2 = (const float*)d_in[9];
    const float* ad2 = (const float*)d_in[10];
    const float* b2  = (const float*)d_in[11];
    const float* Wc  = (const float*)d_in[12];
    const float* bc  = (const float*)d_in[13];

    int n = in_sizes[0] / 128;   // 50000
    int e = in_sizes[1] / 2;     // 850000
    int G = n / NPG;             // 500 graphs
    const int* src = ei;
    const int* dst = ei + e;

    char* ws = (char*)d_ws;
    size_t off = 0;
    auto alloc = [&](size_t bytes) -> void* {
        void* p = ws + off;
        off = (off + bytes + 255) & ~size_t(255);
        return p;
    };
    unsigned short* W1T = (unsigned short*)alloc((size_t)128 * 128 * 2);
    unsigned short* W2T = (unsigned short*)alloc((size_t)128 * 64 * 2);
    int* gcnt = (int*)alloc((size_t)G * 4);
    unsigned short* bucket = (unsigned short*)alloc((size_t)G * CAP * 2);

    float* preds = (float*)d_out;
    float* yout  = preds + (size_t)n * 10;

    int nb256 = (n + 255) / 256;
    int bb = (e + EPB - 1) / EPB;

    // edge bucketing (rebuilt every call: no cross-call state)
    zero_gcnt<<<1, 512, 0, stream>>>(gcnt, G);
    bucket2_kernel<<<bb, 1024, 0, stream>>>(src, dst, gcnt, bucket, e);
    convert_w<<<96, 256, 0, stream>>>(W1, W2, W1T, W2T);

    // the whole network, one block per graph
    graph_fused<<<G, 512, SMEM_BYTES, stream>>>(x, W1T, W2T, as1, ad1, b1,
                                                as2, ad2, b2, Wc, bc,
                                                gcnt, bucket, preds);

    ycopy_kernel<<<nb256, 256, 0, stream>>>(y, yout, n);
}

// Round 11
// 99.610 us; speedup vs baseline: 1.2678x; 1.2678x over previous
//
#include <hip/hip_runtime.h>
#include <math.h>

// ---------------------------------------------------------------------------
// GAT node classifier: 2x GATConv(H=2, concat=False/head-mean) + Linear.
// FULLY FUSED, 2 blocks/CU: one block (512 thr) per graph runs
// gemm1+agg1+gemm2+agg2+cls in 74.7 KB LDS (W read straight from global/L2).
//   prep: bucket edges by graph; W1T/W2T bf16 transposed weights.
//   LDS region reuse timeline:
//     R_HT: sHT (bf16 h^T, zeroed once) -> sOut (f32, after agg2 MFMA)
//     R3:   sX (bf16 x) -> P1 -> sB (layer-1 out) -> P2
//   NaN audit: sHT zeroed once (node cols 112..127 stay 0 both layers);
//   sX rows 100..111 zeroed; sB rows 100..111 zeroed; stale P rows 100..111
//   are finite bf16 (old P1/sB bits) -> only unstored D-rows; sRZ>=100 unused.
// ---------------------------------------------------------------------------

#define NPG 100    // nodes per graph (fixed by problem)
#define CAP 2560   // bucket capacity per graph (mean 1700, +21 sigma)
#define EPB 4096   // edges per bucket-build block

// LDS carve (bytes); total 76520 -> launch with 76544 (74.75 KB, 2 blocks/CU)
#define OFF_HT    0        // 34816: sHT [128 chan][136 node] bf16 -> sOut [112][68] f32
#define OFF_R3    34816    // 30464: sX/P [112][136] bf16 ; sB [112][72] bf16
#define OFF_SCNT  65280    // 6400:  scnt [100][16] u32 (4-bit multiplicities)
#define OFF_SAS   71680    // 896:   sAs [224] f32
#define OFF_SAD   72576    // 896:   sAd [224] f32
#define OFF_SRZ   73472    // 448:   sRZ [112] f32
#define OFF_SWC   73920    // 2560:  sWc [640] f32
#define OFF_SBC   76480    // 40:    sbc [10] f32
#define SMEM_BYTES 76544

typedef __attribute__((ext_vector_type(8))) short bf16x8;
typedef __attribute__((ext_vector_type(4))) float f32x4;

__device__ __forceinline__ float lrelu(float x) { return x > 0.f ? x : 0.2f * x; }

__device__ __forceinline__ unsigned short f2bf(float f) {
    unsigned int u = __float_as_uint(f);
    return (unsigned short)((u + 0x7FFF + ((u >> 16) & 1)) >> 16);  // RNE
}

__global__ void zero_gcnt(int* gcnt, int g) {
    int i = threadIdx.x;
    if (i < g) gcnt[i] = 0;
}

// Two-level bucketing: per-block LDS histogram over graphs, one global
// atomicAdd per (block,graph), then scatter staged edges to reserved ranges.
__global__ __launch_bounds__(1024) void bucket2_kernel(const int* __restrict__ src,
                                                       const int* __restrict__ dst,
                                                       int* gcnt,
                                                       unsigned short* __restrict__ bucket,
                                                       int e) {
    __shared__ int hist[512];
    __shared__ int base[512];
    __shared__ unsigned int staged[EPB];
    int tid = threadIdx.x;
    int e0 = blockIdx.x * EPB;
    int cnt = min(EPB, e - e0);

    for (int i = tid; i < 512; i += 1024) hist[i] = 0;
    __syncthreads();

    for (int i = tid; i < cnt; i += 1024) {
        int d = dst[e0 + i];
        int s = src[e0 + i];
        int g = d / NPG;
        int dloc = d - g * NPG;
        int sloc = s - g * NPG;
        staged[i] = ((unsigned)g << 16) | ((unsigned)dloc << 8) | (unsigned)sloc;
        atomicAdd(&hist[g], 1);
    }
    __syncthreads();

    if (tid < 512) {
        int h = hist[tid];
        base[tid] = h ? atomicAdd(&gcnt[tid], h) : 0;
        hist[tid] = 0;   // reuse as local cursor
    }
    __syncthreads();

    for (int i = tid; i < cnt; i += 1024) {
        unsigned v = staged[i];
        int g = v >> 16;
        int pos = base[g] + atomicAdd(&hist[g], 1);
        if (pos < CAP)
            bucket[(size_t)g * CAP + pos] = (unsigned short)(v & 0xFFFFu);
    }
}

// W1 [128][128], W2 [64][128] f32 -> W1T [c][k=128], W2T [c][k=64] bf16
__global__ __launch_bounds__(256) void convert_w(const float* __restrict__ W1,
                                                 const float* __restrict__ W2,
                                                 unsigned short* __restrict__ W1T,
                                                 unsigned short* __restrict__ W2T) {
    int stride = gridDim.x * 256;
    for (int i = blockIdx.x * 256 + threadIdx.x; i < 128 * 128; i += stride) {
        int k = i >> 7, c = i & 127;
        W1T[c * 128 + k] = f2bf(W1[i]);
    }
    for (int i = blockIdx.x * 256 + threadIdx.x; i < 64 * 128; i += stride) {
        int k = i >> 7, c = i & 127;
        W2T[c * 64 + k] = f2bf(W2[i]);
    }
}

// GEMM phase: sA [rows][SA] bf16 (M=112) @ WT (GLOBAL, [128 cols][K] bf16,
// L2-resident) -> sHT [col*136 + row] bf16 + logits into sAs/sAd.
// Fragment pattern verified on-device (rounds 8-10).
template <int K, int SA>
__device__ __forceinline__ void gemm_block(const unsigned short* sA,
                                           const unsigned short* __restrict__ WT,
                                           const float* __restrict__ a_src,
                                           const float* __restrict__ a_dst,
                                           unsigned short* sHT,
                                           float* sAs, float* sAd,
                                           int lane, int wave) {
    if (wave >= 7) return;   // M = 112 = 7 stripes of 16
    int fr = lane & 15, fk = (lane >> 4) * 8;
    f32x4 acc[8];
#pragma unroll
    for (int t = 0; t < 8; ++t) acc[t] = (f32x4){0.f, 0.f, 0.f, 0.f};
#pragma unroll
    for (int ks = 0; ks < K / 32; ++ks) {
        bf16x8 a = *reinterpret_cast<const bf16x8*>(&sA[(wave * 16 + fr) * SA + ks * 32 + fk]);
#pragma unroll
        for (int t = 0; t < 8; ++t) {
            bf16x8 b = *reinterpret_cast<const bf16x8*>(&WT[(t * 16 + fr) * K + ks * 32 + fk]);
            acc[t] = __builtin_amdgcn_mfma_f32_16x16x32_bf16(a, b, acc[t], 0, 0, 0);
        }
    }
    int rb = wave * 16 + (lane >> 4) * 4;
    float ps0[4] = {0, 0, 0, 0}, ps1[4] = {0, 0, 0, 0};
    float pd0[4] = {0, 0, 0, 0}, pd1[4] = {0, 0, 0, 0};
#pragma unroll
    for (int t = 0; t < 8; ++t) {
        int col = t * 16 + fr;
        float as_ = a_src[col], ad_ = a_dst[col];
#pragma unroll
        for (int j = 0; j < 4; ++j) {
            float v = acc[t][j];
            sHT[col * 136 + rb + j] = f2bf(v);
            if (t < 4) { ps0[j] += v * as_; pd0[j] += v * ad_; }
            else       { ps1[j] += v * as_; pd1[j] += v * ad_; }
        }
    }
#pragma unroll
    for (int off = 1; off <= 8; off <<= 1) {
#pragma unroll
        for (int j = 0; j < 4; ++j) {
            ps0[j] += __shfl_xor(ps0[j], off);
            ps1[j] += __shfl_xor(ps1[j], off);
            pd0[j] += __shfl_xor(pd0[j], off);
            pd1[j] += __shfl_xor(pd1[j], off);
        }
    }
    if (fr == 0) {
#pragma unroll
        for (int j = 0; j < 4; ++j) {
            int d = rb + j;   // up to 111; arrays sized 224
            sAs[d * 2 + 0] = ps0[j];
            sAs[d * 2 + 1] = ps1[j];
            sAd[d * 2 + 0] = pd0[j];
            sAd[d * 2 + 1] = pd1[j];
        }
    }
}

// Aggregation: per head {masked softmax (4-bit multiplicity) -> sP; barrier;
// MFMA P@hT, res += acc/z; barrier}. Stale P rows>=100 are finite bf16 ->
// only unstored D rows; sRZ>=100 unused.
__device__ __forceinline__ void agg_heads(unsigned short* sP,
                                          const unsigned short* sHT,
                                          const unsigned* scnt,
                                          const float* sAs, const float* sAd,
                                          float* sRZ, f32x4 res[4],
                                          int lane, int wave) {
    for (int head = 0; head < 2; ++head) {
        for (int d = wave; d < NPG; d += 8) {
            float adh = sAd[d * 2 + head];
            int s2 = lane + 64;
            unsigned m1 = (scnt[d * 16 + (lane >> 3)] >> ((lane & 7) * 4)) & 15u;
            unsigned m2 = (s2 < NPG) ? ((scnt[d * 16 + (s2 >> 3)] >> ((s2 & 7) * 4)) & 15u) : 0u;
            int si2 = (s2 < NPG) ? s2 : 0;
            float e1 = m1 ? lrelu(sAs[lane * 2 + head] + adh) : -INFINITY;
            float e2 = m2 ? lrelu(sAs[si2 * 2 + head] + adh) : -INFINITY;
            float mx = fmaxf(e1, e2);
            for (int off = 32; off; off >>= 1) mx = fmaxf(mx, __shfl_xor(mx, off));
            float p1 = (float)m1 * __expf(e1 - mx);   // 0 * exp(-inf) = 0
            float p2 = (float)m2 * __expf(e2 - mx);
            float z = p1 + p2;
            for (int off = 32; off; off >>= 1) z += __shfl_xor(z, off);
            sP[d * 136 + lane] = f2bf(p1);
            sP[d * 136 + s2] = f2bf(p2);
            if (lane == 0) sRZ[d] = 1.f / z;
        }
        __syncthreads();
#pragma unroll
        for (int i = 0; i < 4; ++i) {
            int t = wave + 8 * i;
            if (t < 28) {
                int mt = t >> 2, nt = t & 3;
                int arow = mt * 16 + (lane & 15);
                int brow = head * 64 + nt * 16 + (lane & 15);
                int kofs = (lane >> 4) * 8;
                f32x4 acc = (f32x4){0.f, 0.f, 0.f, 0.f};
#pragma unroll
                for (int ks = 0; ks < 4; ++ks) {
                    bf16x8 a = *reinterpret_cast<const bf16x8*>(&sP[arow * 136 + ks * 32 + kofs]);
                    bf16x8 b = *reinterpret_cast<const bf16x8*>(&sHT[brow * 136 + ks * 32 + kofs]);
                    acc = __builtin_amdgcn_mfma_f32_16x16x32_bf16(a, b, acc, 0, 0, 0);
                }
                int dbase = mt * 16 + (lane >> 4) * 4;
#pragma unroll
                for (int r = 0; r < 4; ++r)
                    res[i][r] += acc[r] * sRZ[dbase + r];
            }
        }
        __syncthreads();
    }
}

// One block (512 thr = 8 waves) per graph: whole network in 74.7 KB LDS.
__global__ __launch_bounds__(512, 4) void graph_fused(
    const float* __restrict__ x,
    const unsigned short* __restrict__ W1T,
    const unsigned short* __restrict__ W2T,
    const float* __restrict__ as1, const float* __restrict__ ad1,
    const float* __restrict__ b1,
    const float* __restrict__ as2, const float* __restrict__ ad2,
    const float* __restrict__ b2,
    const float* __restrict__ Wc, const float* __restrict__ bc,
    const int* __restrict__ gcnt, const unsigned short* __restrict__ bucket,
    float* __restrict__ preds) {
    extern __shared__ char smem[];
    unsigned short* sHT  = (unsigned short*)(smem + OFF_HT);
    float*          sOut = (float*)(smem + OFF_HT);            // after agg2
    unsigned short* R3u  = (unsigned short*)(smem + OFF_R3);   // sX -> P1 -> sB -> P2
    unsigned*       scnt = (unsigned*)(smem + OFF_SCNT);
    float*          sAs  = (float*)(smem + OFF_SAS);
    float*          sAd  = (float*)(smem + OFF_SAD);
    float*          sRZ  = (float*)(smem + OFF_SRZ);
    float*          sWc  = (float*)(smem + OFF_SWC);
    float*          sbc  = (float*)(smem + OFF_SBC);

    int g = blockIdx.x, gbase = g * NPG, tid = threadIdx.x;
    int lane = tid & 63, wave = tid >> 6;
    int cnt = min(gcnt[g], CAP);
    float4 z4 = make_float4(0.f, 0.f, 0.f, 0.f);

    // ---- phase A: zero + stage ----
    for (int i = tid; i < 1600; i += 512) scnt[i] = 0;
    for (int i = tid; i < 2176; i += 512)                    // zero sHT (34816 B)
        *reinterpret_cast<float4*>((char*)sHT + i * 16) = z4;
    for (int i = tid; i < NPG * 16; i += 512) {              // x -> sX bf16
        int r = i >> 4, kc = (i & 15) * 8;
        const float* xp = &x[(size_t)(gbase + r) * 128 + kc];
        float4 v0 = *reinterpret_cast<const float4*>(xp);
        float4 v1 = *reinterpret_cast<const float4*>(xp + 4);
        unsigned short t8[8] = {f2bf(v0.x), f2bf(v0.y), f2bf(v0.z), f2bf(v0.w),
                                f2bf(v1.x), f2bf(v1.y), f2bf(v1.z), f2bf(v1.w)};
        *reinterpret_cast<float4*>(&R3u[r * 136 + kc]) = *reinterpret_cast<float4*>(t8);
    }
    for (int i = tid; i < 12 * 17; i += 512) {               // zero sX rows 100..111
        int r = 100 + i / 17, c = (i % 17) * 8;
        *reinterpret_cast<float4*>(&R3u[r * 136 + c]) = z4;
    }
    for (int i = tid; i < 640; i += 512) sWc[i] = Wc[i];
    if (tid < 10) sbc[tid] = bc[tid];
    __syncthreads();
    for (int i = tid; i < cnt; i += 512) {                   // edge multiplicities
        unsigned v = bucket[(size_t)g * CAP + i];
        atomicAdd(&scnt[(v >> 8) * 16 + ((v & 255) >> 3)], 1u << ((v & 7) * 4));
    }
    __syncthreads();

    // ---- layer 1: gemm + agg ----
    gemm_block<128, 136>(R3u, W1T, as1, ad1, sHT, sAs, sAd, lane, wave);
    __syncthreads();

    f32x4 res[4];
#pragma unroll
    for (int i = 0; i < 4; ++i) res[i] = (f32x4){0.f, 0.f, 0.f, 0.f};
    agg_heads(R3u, sHT, scnt, sAs, sAd, sRZ, res, lane, wave);   // P1 over sX

    // epilogue -> sB (bf16 [112][72] at R3, over dead P1): +b1, relu
    {
        unsigned short* sB = R3u;
        int fr = lane & 15;
#pragma unroll
        for (int i = 0; i < 4; ++i) {
            int t = wave + 8 * i;
            if (t < 28) {
                int mt = t >> 2, nt = t & 3;
                int col = nt * 16 + fr;
                float bv = b1[col];
#pragma unroll
                for (int r = 0; r < 4; ++r) {
                    int d = mt * 16 + (lane >> 4) * 4 + r;
                    if (d < NPG)
                        sB[d * 72 + col] = f2bf(fmaxf(0.5f * res[i][r] + bv, 0.f));
                }
            }
        }
        for (int i = tid; i < 12 * 9; i += 512) {            // zero sB rows 100..111
            int r = 100 + i / 9, c = (i % 9) * 8;
            *reinterpret_cast<float4*>(&sB[r * 72 + c]) = z4;
        }
    }
    __syncthreads();

    // ---- layer 2: gemm + agg ----
    gemm_block<64, 72>(R3u, W2T, as2, ad2, sHT, sAs, sAd, lane, wave);
    __syncthreads();

#pragma unroll
    for (int i = 0; i < 4; ++i) res[i] = (f32x4){0.f, 0.f, 0.f, 0.f};
    agg_heads(R3u, sHT, scnt, sAs, sAd, sRZ, res, lane, wave);   // P2 over sB

    // epilogue -> sOut (f32 [112][68] over dead sHT): +b2, no relu
    {
        int fr = lane & 15;
#pragma unroll
        for (int i = 0; i < 4; ++i) {
            int t = wave + 8 * i;
            if (t < 28) {
                int mt = t >> 2, nt = t & 3;
                int col = nt * 16 + fr;
                float bv = b2[col];
#pragma unroll
                for (int r = 0; r < 4; ++r) {
                    int d = mt * 16 + (lane >> 4) * 4 + r;
                    if (d < NPG) sOut[d * 68 + col] = 0.5f * res[i][r] + bv;
                }
            }
        }
    }
    __syncthreads();

    // ---- classifier ----
    for (int idx = tid; idx < NPG * 10; idx += 512) {
        int d = idx / 10, j = idx % 10;
        float acc = sbc[j];
#pragma unroll 8
        for (int c = 0; c < 64; ++c) acc += sOut[d * 68 + c] * sWc[c * 10 + j];
        preds[(size_t)(gbase + d) * 10 + j] = acc;
    }
}

__global__ void ycopy_kernel(const int* __restrict__ y, float* __restrict__ out, int n) {
    int i = blockIdx.x * 256 + threadIdx.x;
    if (i < n) out[i] = (float)y[i];
}

extern "C" void kernel_launch(void* const* d_in, const int* in_sizes, int n_in,
                              void* d_out, int out_size, void* d_ws, size_t ws_size,
                              hipStream_t stream) {
    const float* x   = (const float*)d_in[0];
    const int*   ei  = (const int*)d_in[1];
    const int*   y   = (const int*)d_in[3];
    const float* W1  = (const float*)d_in[4];
    const float* as1 = (const float*)d_in[5];
    const float* ad1 = (const float*)d_in[6];
    const float* b1  = (const float*)d_in[7];
    const float* W2  = (const float*)d_in[8];
    const float* as2 = (const float*)d_in[9];
    const float* ad2 = (const float*)d_in[10];
    const float* b2  = (const float*)d_in[11];
    const float* Wc  = (const float*)d_in[12];
    const float* bc  = (const float*)d_in[13];

    int n = in_sizes[0] / 128;   // 50000
    int e = in_sizes[1] / 2;     // 850000
    int G = n / NPG;             // 500 graphs
    const int* src = ei;
    const int* dst = ei + e;

    char* ws = (char*)d_ws;
    size_t off = 0;
    auto alloc = [&](size_t bytes) -> void* {
        void* p = ws + off;
        off = (off + bytes + 255) & ~size_t(255);
        return p;
    };
    unsigned short* W1T = (unsigned short*)alloc((size_t)128 * 128 * 2);
    unsigned short* W2T = (unsigned short*)alloc((size_t)128 * 64 * 2);
    int* gcnt = (int*)alloc((size_t)G * 4);
    unsigned short* bucket = (unsigned short*)alloc((size_t)G * CAP * 2);

    float* preds = (float*)d_out;
    float* yout  = preds + (size_t)n * 10;

    int nb256 = (n + 255) / 256;
    int bb = (e + EPB - 1) / EPB;

    // edge bucketing (rebuilt every call: no cross-call state)
    zero_gcnt<<<1, 512, 0, stream>>>(gcnt, G);
    bucket2_kernel<<<bb, 1024, 0, stream>>>(src, dst, gcnt, bucket, e);
    convert_w<<<96, 256, 0, stream>>>(W1, W2, W1T, W2T);

    // the whole network, one block per graph (2 blocks/CU)
    graph_fused<<<G, 512, SMEM_BYTES, stream>>>(x, W1T, W2T, as1, ad1, b1,
                                                as2, ad2, b2, Wc, bc,
                                                gcnt, bucket, preds);

    ycopy_kernel<<<nb256, 256, 0, stream>>>(y, yout, n);
}

// Round 12
// 95.771 us; speedup vs baseline: 1.3186x; 1.0401x over previous
//
#include <hip/hip_runtime.h>
#include <math.h>

// ---------------------------------------------------------------------------
// GAT node classifier: 2x GATConv(H=2, concat=False/head-mean) + Linear.
// FULLY FUSED, 1024 thr/block, 2 blocks/CU (32 waves/CU): one block per graph
// runs gemm1+agg1+gemm2+agg2+cls+ycopy in 74.75 KB LDS; W read from L2.
//   prep: convert_w (+gcnt zero) ; bucket2 (edge bucketing by graph).
//   LDS region reuse: R_HT: sHT (bf16 h^T) -> sOut (f32 after agg2);
//                     R3:   sX -> P1 -> sB -> P2.
//   Wave decomposition (16 waves):
//     gemm: wave w<14: stripe=w>>1 (16 rows), head-half=w&1 (4 col-tiles);
//           logits per-head wave-local, shfl-reduced over fr.
//     agg:  softmax rows d = wave+16k (7 rounds); MFMA 28 tiles in 2 rounds.
//   NaN audit: sHT zeroed once (node cols 112..127 stay 0 both layers); sX/sB
//   rows 100..111 zeroed; stale P rows >=100 finite bf16 -> only unstored
//   D-rows; sRZ >=100 unused.
// ---------------------------------------------------------------------------

#define NPG 100    // nodes per graph (fixed by problem)
#define CAP 2560   // bucket capacity per graph (mean 1700, +21 sigma)
#define EPB 4096   // edges per bucket-build block

// LDS carve (bytes); total 76520 -> launch with 76544 (74.75 KB, 2 blocks/CU)
#define OFF_HT    0        // 34816: sHT [128 chan][136 node] bf16 -> sOut [112][68] f32
#define OFF_R3    34816    // 30464: sX/P [112][136] bf16 ; sB [112][72] bf16
#define OFF_SCNT  65280    // 6400:  scnt [100][16] u32 (4-bit multiplicities)
#define OFF_SAS   71680    // 896:   sAs [224] f32
#define OFF_SAD   72576    // 896:   sAd [224] f32
#define OFF_SRZ   73472    // 448:   sRZ [112] f32
#define OFF_SWC   73920    // 2560:  sWc [640] f32
#define OFF_SBC   76480    // 40:    sbc [10] f32
#define SMEM_BYTES 76544

typedef __attribute__((ext_vector_type(8))) short bf16x8;
typedef __attribute__((ext_vector_type(4))) float f32x4;

__device__ __forceinline__ float lrelu(float x) { return x > 0.f ? x : 0.2f * x; }

__device__ __forceinline__ unsigned short f2bf(float f) {
    unsigned int u = __float_as_uint(f);
    return (unsigned short)((u + 0x7FFF + ((u >> 16) & 1)) >> 16);  // RNE
}

// Two-level bucketing: per-block LDS histogram over graphs, one global
// atomicAdd per (block,graph), then scatter staged edges to reserved ranges.
__global__ __launch_bounds__(1024) void bucket2_kernel(const int* __restrict__ src,
                                                       const int* __restrict__ dst,
                                                       int* gcnt,
                                                       unsigned short* __restrict__ bucket,
                                                       int e) {
    __shared__ int hist[512];
    __shared__ int base[512];
    __shared__ unsigned int staged[EPB];
    int tid = threadIdx.x;
    int e0 = blockIdx.x * EPB;
    int cnt = min(EPB, e - e0);

    for (int i = tid; i < 512; i += 1024) hist[i] = 0;
    __syncthreads();

    for (int i = tid; i < cnt; i += 1024) {
        int d = dst[e0 + i];
        int s = src[e0 + i];
        int g = d / NPG;
        int dloc = d - g * NPG;
        int sloc = s - g * NPG;
        staged[i] = ((unsigned)g << 16) | ((unsigned)dloc << 8) | (unsigned)sloc;
        atomicAdd(&hist[g], 1);
    }
    __syncthreads();

    if (tid < 512) {
        int h = hist[tid];
        base[tid] = h ? atomicAdd(&gcnt[tid], h) : 0;
        hist[tid] = 0;   // reuse as local cursor
    }
    __syncthreads();

    for (int i = tid; i < cnt; i += 1024) {
        unsigned v = staged[i];
        int g = v >> 16;
        int pos = base[g] + atomicAdd(&hist[g], 1);
        if (pos < CAP)
            bucket[(size_t)g * CAP + pos] = (unsigned short)(v & 0xFFFFu);
    }
}

// W1 [128][128], W2 [64][128] f32 -> W1T/W2T bf16 transposed; also zeroes gcnt
// (runs before bucket2 in stream order; replaces a separate 1-block launch).
__global__ __launch_bounds__(256) void convert_w(const float* __restrict__ W1,
                                                 const float* __restrict__ W2,
                                                 unsigned short* __restrict__ W1T,
                                                 unsigned short* __restrict__ W2T,
                                                 int* gcnt, int G) {
    int stride = gridDim.x * 256;
    int t0 = blockIdx.x * 256 + threadIdx.x;
    for (int i = t0; i < 128 * 128; i += stride) {
        int k = i >> 7, c = i & 127;
        W1T[c * 128 + k] = f2bf(W1[i]);
    }
    for (int i = t0; i < 64 * 128; i += stride) {
        int k = i >> 7, c = i & 127;
        W2T[c * 64 + k] = f2bf(W2[i]);
    }
    for (int i = t0; i < G; i += stride) gcnt[i] = 0;
}

// GEMM phase (16 waves): wave w<14: stripe s=w>>1 (rows s*16..s*16+15),
// head-half h=w&1 (col tiles 4h..4h+3). sA [rows][SA] bf16 @ WT (GLOBAL,
// [128 cols][K] bf16, L2-resident) -> sHT[col*136+row] bf16 (packed 8B
// writes) + per-head logits into sAs/sAd. Fragment pattern verified on-device
// (rounds 8-11): a row=lane&15, k=(lane>>4)*8+j; D col=lane&15,
// row=(lane>>4)*4+j.
template <int K, int SA>
__device__ __forceinline__ void gemm_block(const unsigned short* sA,
                                           const unsigned short* __restrict__ WT,
                                           const float* __restrict__ a_src,
                                           const float* __restrict__ a_dst,
                                           unsigned short* sHT,
                                           float* sAs, float* sAd,
                                           int lane, int wave) {
    if (wave >= 14) return;   // 7 stripes x 2 head-halves
    int s = wave >> 1, h = wave & 1;
    int fr = lane & 15, fk = (lane >> 4) * 8;
    f32x4 acc[4];
#pragma unroll
    for (int t = 0; t < 4; ++t) acc[t] = (f32x4){0.f, 0.f, 0.f, 0.f};
#pragma unroll
    for (int ks = 0; ks < K / 32; ++ks) {
        bf16x8 a = *reinterpret_cast<const bf16x8*>(&sA[(s * 16 + fr) * SA + ks * 32 + fk]);
#pragma unroll
        for (int t = 0; t < 4; ++t) {
            bf16x8 b = *reinterpret_cast<const bf16x8*>(
                &WT[((h * 4 + t) * 16 + fr) * K + ks * 32 + fk]);
            acc[t] = __builtin_amdgcn_mfma_f32_16x16x32_bf16(a, b, acc[t], 0, 0, 0);
        }
    }
    int rb = s * 16 + (lane >> 4) * 4;
    float ps[4] = {0, 0, 0, 0}, pd[4] = {0, 0, 0, 0};
#pragma unroll
    for (int t = 0; t < 4; ++t) {
        int col = (h * 4 + t) * 16 + fr;
        float as_ = a_src[col], ad_ = a_dst[col];
        unsigned u0, u1;
        {
            float v0 = acc[t][0], v1 = acc[t][1], v2 = acc[t][2], v3 = acc[t][3];
            ps[0] += v0 * as_; pd[0] += v0 * ad_;
            ps[1] += v1 * as_; pd[1] += v1 * ad_;
            ps[2] += v2 * as_; pd[2] += v2 * ad_;
            ps[3] += v3 * as_; pd[3] += v3 * ad_;
            u0 = (unsigned)f2bf(v0) | ((unsigned)f2bf(v1) << 16);
            u1 = (unsigned)f2bf(v2) | ((unsigned)f2bf(v3) << 16);
        }
        *reinterpret_cast<uint2*>(&sHT[col * 136 + rb]) = make_uint2(u0, u1);
    }
#pragma unroll
    for (int off = 1; off <= 8; off <<= 1) {
#pragma unroll
        for (int j = 0; j < 4; ++j) {
            ps[j] += __shfl_xor(ps[j], off);
            pd[j] += __shfl_xor(pd[j], off);
        }
    }
    if (fr == 0) {
#pragma unroll
        for (int j = 0; j < 4; ++j) {
            int d = rb + j;   // up to 111; arrays sized 224
            sAs[d * 2 + h] = ps[j];
            sAd[d * 2 + h] = pd[j];
        }
    }
}

// Aggregation (16 waves, heads sequential): per head {masked softmax (4-bit
// multiplicity), rows stride 16 -> sP; barrier; MFMA 28 tiles in 2 rounds,
// res += acc/z; barrier}.
__device__ __forceinline__ void agg_heads(unsigned short* sP,
                                          const unsigned short* sHT,
                                          const unsigned* scnt,
                                          const float* sAs, const float* sAd,
                                          float* sRZ, f32x4 res[2],
                                          int lane, int wave) {
    for (int head = 0; head < 2; ++head) {
        for (int d = wave; d < NPG; d += 16) {
            float adh = sAd[d * 2 + head];
            int s2 = lane + 64;
            unsigned m1 = (scnt[d * 16 + (lane >> 3)] >> ((lane & 7) * 4)) & 15u;
            unsigned m2 = (s2 < NPG) ? ((scnt[d * 16 + (s2 >> 3)] >> ((s2 & 7) * 4)) & 15u) : 0u;
            int si2 = (s2 < NPG) ? s2 : 0;
            float e1 = m1 ? lrelu(sAs[lane * 2 + head] + adh) : -INFINITY;
            float e2 = m2 ? lrelu(sAs[si2 * 2 + head] + adh) : -INFINITY;
            float mx = fmaxf(e1, e2);
            for (int off = 32; off; off >>= 1) mx = fmaxf(mx, __shfl_xor(mx, off));
            float p1 = (float)m1 * __expf(e1 - mx);   // 0 * exp(-inf) = 0
            float p2 = (float)m2 * __expf(e2 - mx);
            float z = p1 + p2;
            for (int off = 32; off; off >>= 1) z += __shfl_xor(z, off);
            sP[d * 136 + lane] = f2bf(p1);
            sP[d * 136 + s2] = f2bf(p2);
            if (lane == 0) sRZ[d] = 1.f / z;
        }
        __syncthreads();
#pragma unroll
        for (int i = 0; i < 2; ++i) {
            int t = wave + 16 * i;
            if (t < 28) {
                int mt = t >> 2, nt = t & 3;
                int arow = mt * 16 + (lane & 15);
                int brow = head * 64 + nt * 16 + (lane & 15);
                int kofs = (lane >> 4) * 8;
                f32x4 acc = (f32x4){0.f, 0.f, 0.f, 0.f};
#pragma unroll
                for (int ks = 0; ks < 4; ++ks) {
                    bf16x8 a = *reinterpret_cast<const bf16x8*>(&sP[arow * 136 + ks * 32 + kofs]);
                    bf16x8 b = *reinterpret_cast<const bf16x8*>(&sHT[brow * 136 + ks * 32 + kofs]);
                    acc = __builtin_amdgcn_mfma_f32_16x16x32_bf16(a, b, acc, 0, 0, 0);
                }
                int dbase = mt * 16 + (lane >> 4) * 4;
#pragma unroll
                for (int r = 0; r < 4; ++r)
                    res[i][r] += acc[r] * sRZ[dbase + r];
            }
        }
        __syncthreads();
    }
}

// One block (1024 thr = 16 waves) per graph: whole network in 74.75 KB LDS.
__global__ __launch_bounds__(1024, 8) void graph_fused(
    const float* __restrict__ x,
    const unsigned short* __restrict__ W1T,
    const unsigned short* __restrict__ W2T,
    const float* __restrict__ as1, const float* __restrict__ ad1,
    const float* __restrict__ b1,
    const float* __restrict__ as2, const float* __restrict__ ad2,
    const float* __restrict__ b2,
    const float* __restrict__ Wc, const float* __restrict__ bc,
    const int* __restrict__ gcnt, const unsigned short* __restrict__ bucket,
    const int* __restrict__ y,
    float* __restrict__ preds, float* __restrict__ yout) {
    extern __shared__ char smem[];
    unsigned short* sHT  = (unsigned short*)(smem + OFF_HT);
    float*          sOut = (float*)(smem + OFF_HT);            // after agg2
    unsigned short* R3u  = (unsigned short*)(smem + OFF_R3);   // sX -> P1 -> sB -> P2
    unsigned*       scnt = (unsigned*)(smem + OFF_SCNT);
    float*          sAs  = (float*)(smem + OFF_SAS);
    float*          sAd  = (float*)(smem + OFF_SAD);
    float*          sRZ  = (float*)(smem + OFF_SRZ);
    float*          sWc  = (float*)(smem + OFF_SWC);
    float*          sbc  = (float*)(smem + OFF_SBC);

    int g = blockIdx.x, gbase = g * NPG, tid = threadIdx.x;
    int lane = tid & 63, wave = tid >> 6;
    int cnt = min(gcnt[g], CAP);
    float4 z4 = make_float4(0.f, 0.f, 0.f, 0.f);

    // ---- phase A: zero + stage ----
    for (int i = tid; i < 1600; i += 1024) scnt[i] = 0;
    for (int i = tid; i < 2176; i += 1024)                   // zero sHT (34816 B)
        *reinterpret_cast<float4*>((char*)sHT + i * 16) = z4;
    for (int i = tid; i < NPG * 16; i += 1024) {             // x -> sX bf16
        int r = i >> 4, kc = (i & 15) * 8;
        const float* xp = &x[(size_t)(gbase + r) * 128 + kc];
        float4 v0 = *reinterpret_cast<const float4*>(xp);
        float4 v1 = *reinterpret_cast<const float4*>(xp + 4);
        unsigned short t8[8] = {f2bf(v0.x), f2bf(v0.y), f2bf(v0.z), f2bf(v0.w),
                                f2bf(v1.x), f2bf(v1.y), f2bf(v1.z), f2bf(v1.w)};
        *reinterpret_cast<float4*>(&R3u[r * 136 + kc]) = *reinterpret_cast<float4*>(t8);
    }
    for (int i = tid; i < 12 * 17; i += 1024) {              // zero sX rows 100..111
        int r = 100 + i / 17, c = (i % 17) * 8;
        *reinterpret_cast<float4*>(&R3u[r * 136 + c]) = z4;
    }
    for (int i = tid; i < 640; i += 1024) sWc[i] = Wc[i];
    if (tid < 10) sbc[tid] = bc[tid];
    if (tid < NPG) yout[gbase + tid] = (float)y[gbase + tid];   // fused ycopy
    __syncthreads();
    for (int i = tid; i < cnt; i += 1024) {                  // edge multiplicities
        unsigned v = bucket[(size_t)g * CAP + i];
        atomicAdd(&scnt[(v >> 8) * 16 + ((v & 255) >> 3)], 1u << ((v & 7) * 4));
    }
    __syncthreads();

    // ---- layer 1: gemm + agg ----
    gemm_block<128, 136>(R3u, W1T, as1, ad1, sHT, sAs, sAd, lane, wave);
    __syncthreads();

    f32x4 res[2];
    res[0] = (f32x4){0.f, 0.f, 0.f, 0.f};
    res[1] = (f32x4){0.f, 0.f, 0.f, 0.f};
    agg_heads(R3u, sHT, scnt, sAs, sAd, sRZ, res, lane, wave);   // P1 over sX

    // epilogue -> sB (bf16 [112][72] at R3, over dead P1): +b1, relu
    {
        unsigned short* sB = R3u;
        int fr = lane & 15;
#pragma unroll
        for (int i = 0; i < 2; ++i) {
            int t = wave + 16 * i;
            if (t < 28) {
                int mt = t >> 2, nt = t & 3;
                int col = nt * 16 + fr;
                float bv = b1[col];
#pragma unroll
                for (int r = 0; r < 4; ++r) {
                    int d = mt * 16 + (lane >> 4) * 4 + r;
                    if (d < NPG)
                        sB[d * 72 + col] = f2bf(fmaxf(0.5f * res[i][r] + bv, 0.f));
                }
            }
        }
        for (int i = tid; i < 12 * 9; i += 1024) {           // zero sB rows 100..111
            int r = 100 + i / 9, c = (i % 9) * 8;
            *reinterpret_cast<float4*>(&sB[r * 72 + c]) = z4;
        }
    }
    __syncthreads();

    // ---- layer 2: gemm + agg ----
    gemm_block<64, 72>(R3u, W2T, as2, ad2, sHT, sAs, sAd, lane, wave);
    __syncthreads();

    res[0] = (f32x4){0.f, 0.f, 0.f, 0.f};
    res[1] = (f32x4){0.f, 0.f, 0.f, 0.f};
    agg_heads(R3u, sHT, scnt, sAs, sAd, sRZ, res, lane, wave);   // P2 over sB

    // epilogue -> sOut (f32 [112][68] over dead sHT): +b2, no relu
    {
        int fr = lane & 15;
#pragma unroll
        for (int i = 0; i < 2; ++i) {
            int t = wave + 16 * i;
            if (t < 28) {
                int mt = t >> 2, nt = t & 3;
                int col = nt * 16 + fr;
                float bv = b2[col];
#pragma unroll
                for (int r = 0; r < 4; ++r) {
                    int d = mt * 16 + (lane >> 4) * 4 + r;
                    if (d < NPG) sOut[d * 68 + col] = 0.5f * res[i][r] + bv;
                }
            }
        }
    }
    __syncthreads();

    // ---- classifier ----
    for (int idx = tid; idx < NPG * 10; idx += 1024) {
        int d = idx / 10, j = idx % 10;
        float acc = sbc[j];
#pragma unroll 8
        for (int c = 0; c < 64; ++c) acc += sOut[d * 68 + c] * sWc[c * 10 + j];
        preds[(size_t)(gbase + d) * 10 + j] = acc;
    }
}

extern "C" void kernel_launch(void* const* d_in, const int* in_sizes, int n_in,
                              void* d_out, int out_size, void* d_ws, size_t ws_size,
                              hipStream_t stream) {
    const float* x   = (const float*)d_in[0];
    const int*   ei  = (const int*)d_in[1];
    const int*   y   = (const int*)d_in[3];
    const float* W1  = (const float*)d_in[4];
    const float* as1 = (const float*)d_in[5];
    const float* ad1 = (const float*)d_in[6];
    const float* b1  = (const float*)d_in[7];
    const float* W2  = (const float*)d_in[8];
    const float* as2 = (const float*)d_in[9];
    const float* ad2 = (const float*)d_in[10];
    const float* b2  = (const float*)d_in[11];
    const float* Wc  = (const float*)d_in[12];
    const float* bc  = (const float*)d_in[13];

    int n = in_sizes[0] / 128;   // 50000
    int e = in_sizes[1] / 2;     // 850000
    int G = n / NPG;             // 500 graphs
    const int* src = ei;
    const int* dst = ei + e;

    char* ws = (char*)d_ws;
    size_t off = 0;
    auto alloc = [&](size_t bytes) -> void* {
        void* p = ws + off;
        off = (off + bytes + 255) & ~size_t(255);
        return p;
    };
    unsigned short* W1T = (unsigned short*)alloc((size_t)128 * 128 * 2);
    unsigned short* W2T = (unsigned short*)alloc((size_t)128 * 64 * 2);
    int* gcnt = (int*)alloc((size_t)G * 4);
    unsigned short* bucket = (unsigned short*)alloc((size_t)G * CAP * 2);

    float* preds = (float*)d_out;
    float* yout  = preds + (size_t)n * 10;

    int bb = (e + EPB - 1) / EPB;

    // prep: weight convert + gcnt zero, then edge bucketing
    convert_w<<<96, 256, 0, stream>>>(W1, W2, W1T, W2T, gcnt, G);
    bucket2_kernel<<<bb, 1024, 0, stream>>>(src, dst, gcnt, bucket, e);

    // the whole network, one block per graph (2 blocks/CU, 32 waves/CU)
    graph_fused<<<G, 1024, SMEM_BYTES, stream>>>(x, W1T, W2T, as1, ad1, b1,
                                                 as2, ad2, b2, Wc, bc,
                                                 gcnt, bucket, y, preds, yout);
}

// Round 13
// 78.799 us; speedup vs baseline: 1.6026x; 1.2154x over previous
//
#include <hip/hip_runtime.h>
#include <math.h>

// ---------------------------------------------------------------------------
// GAT node classifier: 2x GATConv(H=2, concat=False/head-mean) + Linear.
// FULLY FUSED, 1024 thr/block, 2 blocks/CU: one block per graph runs
// gemm1+agg1+gemm2+agg2+cls+ycopy in ~75 KB LDS; W read from L2.
// Round-13 changes (VALU-work reduction; kernel is throughput- not
// latency-bound per r12 counters):
//   - softmax WITHOUT max-subtraction (logits bounded |e|<~6; shift-invariant)
//     -> kills the 6-round max shfl chain per row-head.
//   - lane handles sources (2l, 2l+1): one scnt dword + one float4 sAs read
//     covers both sources x both heads; P written as packed b32 (cvt_pk).
//   - v_cvt_pk_bf16_f32 inline asm replaces manual f2bf everywhere (1 instr
//     per 2 conversions vs ~8 int ops).
//   - cls reads sOut via float4.
//   NaN audit: sHT zeroed once; sX/sB rows 100..111 zeroed; sAs/sAd[224..255]
//   zeroed (softmax float4 reads reach 255); p guarded by mult?:0 cndmask;
//   stale P rows >=100 finite -> only unstored D-rows; sRZ>=100 unused.
// ---------------------------------------------------------------------------

#define NPG 100    // nodes per graph (fixed by problem)
#define CAP 2560   // bucket capacity per graph (mean 1700, +21 sigma)
#define EPB 4096   // edges per bucket-build block

// LDS carve (bytes); total 76776 -> launch with 76800 (75 KB, 2 blocks/CU)
#define OFF_HT    0        // 34816: sHT [128 chan][136 node] bf16 -> sOut [112][68] f32
#define OFF_R3    34816    // 30464: sX/P [112][136] bf16 ; sB [112][72] bf16
#define OFF_SCNT  65280    // 6400:  scnt [100][16] u32 (4-bit multiplicities)
#define OFF_SAS   71680    // 1024:  sAs [256] f32 (tail zeroed)
#define OFF_SAD   72704    // 1024:  sAd [256] f32 (tail zeroed)
#define OFF_SRZ   73728    // 448:   sRZ [112] f32
#define OFF_SWC   74176    // 2560:  sWc [640] f32
#define OFF_SBC   76736    // 40:    sbc [10] f32
#define SMEM_BYTES 76800

typedef __attribute__((ext_vector_type(8))) short bf16x8;
typedef __attribute__((ext_vector_type(4))) float f32x4;

__device__ __forceinline__ float lrelu(float x) { return x > 0.f ? x : 0.2f * x; }

// one instruction, 2 f32 -> packed 2 bf16 (RNE); no builtin on gfx950
__device__ __forceinline__ unsigned cvt_pk(float lo, float hi) {
    unsigned r;
    asm("v_cvt_pk_bf16_f32 %0, %1, %2" : "=v"(r) : "v"(lo), "v"(hi));
    return r;
}

__device__ __forceinline__ unsigned short f2bf(float f) {
    unsigned int u = __float_as_uint(f);
    return (unsigned short)((u + 0x7FFF + ((u >> 16) & 1)) >> 16);  // RNE
}

// Two-level bucketing: per-block LDS histogram over graphs, one global
// atomicAdd per (block,graph), then scatter staged edges to reserved ranges.
__global__ __launch_bounds__(1024) void bucket2_kernel(const int* __restrict__ src,
                                                       const int* __restrict__ dst,
                                                       int* gcnt,
                                                       unsigned short* __restrict__ bucket,
                                                       int e) {
    __shared__ int hist[512];
    __shared__ int base[512];
    __shared__ unsigned int staged[EPB];
    int tid = threadIdx.x;
    int e0 = blockIdx.x * EPB;
    int cnt = min(EPB, e - e0);

    for (int i = tid; i < 512; i += 1024) hist[i] = 0;
    __syncthreads();

    for (int i = tid; i < cnt; i += 1024) {
        int d = dst[e0 + i];
        int s = src[e0 + i];
        int g = d / NPG;
        int dloc = d - g * NPG;
        int sloc = s - g * NPG;
        staged[i] = ((unsigned)g << 16) | ((unsigned)dloc << 8) | (unsigned)sloc;
        atomicAdd(&hist[g], 1);
    }
    __syncthreads();

    if (tid < 512) {
        int h = hist[tid];
        base[tid] = h ? atomicAdd(&gcnt[tid], h) : 0;
        hist[tid] = 0;   // reuse as local cursor
    }
    __syncthreads();

    for (int i = tid; i < cnt; i += 1024) {
        unsigned v = staged[i];
        int g = v >> 16;
        int pos = base[g] + atomicAdd(&hist[g], 1);
        if (pos < CAP)
            bucket[(size_t)g * CAP + pos] = (unsigned short)(v & 0xFFFFu);
    }
}

// W1 [128][128], W2 [64][128] f32 -> W1T/W2T bf16 transposed; also zeroes gcnt.
__global__ __launch_bounds__(256) void convert_w(const float* __restrict__ W1,
                                                 const float* __restrict__ W2,
                                                 unsigned short* __restrict__ W1T,
                                                 unsigned short* __restrict__ W2T,
                                                 int* gcnt, int G) {
    int stride = gridDim.x * 256;
    int t0 = blockIdx.x * 256 + threadIdx.x;
    for (int i = t0; i < 128 * 128; i += stride) {
        int k = i >> 7, c = i & 127;
        W1T[c * 128 + k] = f2bf(W1[i]);
    }
    for (int i = t0; i < 64 * 128; i += stride) {
        int k = i >> 7, c = i & 127;
        W2T[c * 64 + k] = f2bf(W2[i]);
    }
    for (int i = t0; i < G; i += stride) gcnt[i] = 0;
}

// GEMM phase (16 waves): wave w<14: stripe s=w>>1 (16 rows), head-half h=w&1
// (4 col-tiles). sA [rows][SA] bf16 @ WT (GLOBAL [128 cols][K] bf16, L2) ->
// sHT[col*136+row] bf16 (packed 8B) + per-head logits into sAs/sAd.
// Fragment pattern verified on-device (rounds 8-12).
template <int K, int SA>
__device__ __forceinline__ void gemm_block(const unsigned short* sA,
                                           const unsigned short* __restrict__ WT,
                                           const float* __restrict__ a_src,
                                           const float* __restrict__ a_dst,
                                           unsigned short* sHT,
                                           float* sAs, float* sAd,
                                           int lane, int wave) {
    if (wave >= 14) return;   // 7 stripes x 2 head-halves
    int s = wave >> 1, h = wave & 1;
    int fr = lane & 15, fk = (lane >> 4) * 8;
    f32x4 acc[4];
#pragma unroll
    for (int t = 0; t < 4; ++t) acc[t] = (f32x4){0.f, 0.f, 0.f, 0.f};
#pragma unroll
    for (int ks = 0; ks < K / 32; ++ks) {
        bf16x8 a = *reinterpret_cast<const bf16x8*>(&sA[(s * 16 + fr) * SA + ks * 32 + fk]);
#pragma unroll
        for (int t = 0; t < 4; ++t) {
            bf16x8 b = *reinterpret_cast<const bf16x8*>(
                &WT[((h * 4 + t) * 16 + fr) * K + ks * 32 + fk]);
            acc[t] = __builtin_amdgcn_mfma_f32_16x16x32_bf16(a, b, acc[t], 0, 0, 0);
        }
    }
    int rb = s * 16 + (lane >> 4) * 4;
    float ps[4] = {0, 0, 0, 0}, pd[4] = {0, 0, 0, 0};
#pragma unroll
    for (int t = 0; t < 4; ++t) {
        int col = (h * 4 + t) * 16 + fr;
        float as_ = a_src[col], ad_ = a_dst[col];
        float v0 = acc[t][0], v1 = acc[t][1], v2 = acc[t][2], v3 = acc[t][3];
        ps[0] += v0 * as_; pd[0] += v0 * ad_;
        ps[1] += v1 * as_; pd[1] += v1 * ad_;
        ps[2] += v2 * as_; pd[2] += v2 * ad_;
        ps[3] += v3 * as_; pd[3] += v3 * ad_;
        *reinterpret_cast<uint2*>(&sHT[col * 136 + rb]) =
            make_uint2(cvt_pk(v0, v1), cvt_pk(v2, v3));
    }
#pragma unroll
    for (int off = 1; off <= 8; off <<= 1) {
#pragma unroll
        for (int j = 0; j < 4; ++j) {
            ps[j] += __shfl_xor(ps[j], off);
            pd[j] += __shfl_xor(pd[j], off);
        }
    }
    if (fr == 0) {
#pragma unroll
        for (int j = 0; j < 4; ++j) {
            int d = rb + j;   // up to 111; arrays sized 256
            sAs[d * 2 + h] = ps[j];
            sAd[d * 2 + h] = pd[j];
        }
    }
}

// Aggregation (16 waves, heads sequential): per head {no-max softmax (4-bit
// multiplicity, lane owns sources 2l/2l+1) -> sP packed b32; barrier; MFMA
// 28 tiles in 2 rounds, res += acc/z; barrier}.
__device__ __forceinline__ void agg_heads(unsigned short* sP,
                                          const unsigned short* sHT,
                                          const unsigned* scnt,
                                          const float* sAs, const float* sAd,
                                          float* sRZ, f32x4 res[2],
                                          int lane, int wave) {
    for (int head = 0; head < 2; ++head) {
        for (int d = wave; d < NPG; d += 16) {
            float adh = sAd[d * 2 + head];
            unsigned w = scnt[d * 16 + (lane >> 2)];
            int sh = (lane & 3) * 8;
            unsigned m0 = (w >> sh) & 15u;
            unsigned m1 = (w >> (sh + 4)) & 15u;
            // sAs[4l..4l+3] = {s0.h0, s0.h1, s1.h0, s1.h1}; tail (>=224) zeroed
            float4 a4 = *reinterpret_cast<const float4*>(&sAs[lane * 4]);
            float e0 = (head ? a4.y : a4.x) + adh;
            float e1 = (head ? a4.w : a4.z) + adh;
            // no max-subtraction: |e| <~6 by construction; softmax shift-inv.
            float p0 = m0 ? (float)m0 * __expf(lrelu(e0)) : 0.f;
            float p1 = m1 ? (float)m1 * __expf(lrelu(e1)) : 0.f;
            float z = p0 + p1;
            for (int off = 32; off; off >>= 1) z += __shfl_xor(z, off);
            *reinterpret_cast<unsigned*>(&sP[d * 136 + lane * 2]) = cvt_pk(p0, p1);
            if (lane == 0) sRZ[d] = 1.f / z;
        }
        __syncthreads();
#pragma unroll
        for (int i = 0; i < 2; ++i) {
            int t = wave + 16 * i;
            if (t < 28) {
                int mt = t >> 2, nt = t & 3;
                int arow = mt * 16 + (lane & 15);
                int brow = head * 64 + nt * 16 + (lane & 15);
                int kofs = (lane >> 4) * 8;
                f32x4 acc = (f32x4){0.f, 0.f, 0.f, 0.f};
#pragma unroll
                for (int ks = 0; ks < 4; ++ks) {
                    bf16x8 a = *reinterpret_cast<const bf16x8*>(&sP[arow * 136 + ks * 32 + kofs]);
                    bf16x8 b = *reinterpret_cast<const bf16x8*>(&sHT[brow * 136 + ks * 32 + kofs]);
                    acc = __builtin_amdgcn_mfma_f32_16x16x32_bf16(a, b, acc, 0, 0, 0);
                }
                int dbase = mt * 16 + (lane >> 4) * 4;
#pragma unroll
                for (int r = 0; r < 4; ++r)
                    res[i][r] += acc[r] * sRZ[dbase + r];
            }
        }
        __syncthreads();
    }
}

// One block (1024 thr = 16 waves) per graph: whole network in 75 KB LDS.
__global__ __launch_bounds__(1024, 8) void graph_fused(
    const float* __restrict__ x,
    const unsigned short* __restrict__ W1T,
    const unsigned short* __restrict__ W2T,
    const float* __restrict__ as1, const float* __restrict__ ad1,
    const float* __restrict__ b1,
    const float* __restrict__ as2, const float* __restrict__ ad2,
    const float* __restrict__ b2,
    const float* __restrict__ Wc, const float* __restrict__ bc,
    const int* __restrict__ gcnt, const unsigned short* __restrict__ bucket,
    const int* __restrict__ y,
    float* __restrict__ preds, float* __restrict__ yout) {
    extern __shared__ char smem[];
    unsigned short* sHT  = (unsigned short*)(smem + OFF_HT);
    float*          sOut = (float*)(smem + OFF_HT);            // after agg2
    unsigned short* R3u  = (unsigned short*)(smem + OFF_R3);   // sX -> P1 -> sB -> P2
    unsigned*       scnt = (unsigned*)(smem + OFF_SCNT);
    float*          sAs  = (float*)(smem + OFF_SAS);
    float*          sAd  = (float*)(smem + OFF_SAD);
    float*          sRZ  = (float*)(smem + OFF_SRZ);
    float*          sWc  = (float*)(smem + OFF_SWC);
    float*          sbc  = (float*)(smem + OFF_SBC);

    int g = blockIdx.x, gbase = g * NPG, tid = threadIdx.x;
    int lane = tid & 63, wave = tid >> 6;
    int cnt = min(gcnt[g], CAP);
    float4 z4 = make_float4(0.f, 0.f, 0.f, 0.f);

    // ---- phase A: zero + stage ----
    for (int i = tid; i < 1600; i += 1024) scnt[i] = 0;
    for (int i = tid; i < 2176; i += 1024)                   // zero sHT (34816 B)
        *reinterpret_cast<float4*>((char*)sHT + i * 16) = z4;
    for (int i = tid; i < NPG * 16; i += 1024) {             // x -> sX bf16
        int r = i >> 4, kc = (i & 15) * 8;
        const float* xp = &x[(size_t)(gbase + r) * 128 + kc];
        float4 v0 = *reinterpret_cast<const float4*>(xp);
        float4 v1 = *reinterpret_cast<const float4*>(xp + 4);
        uint4 u = make_uint4(cvt_pk(v0.x, v0.y), cvt_pk(v0.z, v0.w),
                             cvt_pk(v1.x, v1.y), cvt_pk(v1.z, v1.w));
        *reinterpret_cast<uint4*>(&R3u[r * 136 + kc]) = u;
    }
    for (int i = tid; i < 12 * 17; i += 1024) {              // zero sX rows 100..111
        int r = 100 + i / 17, c = (i % 17) * 8;
        *reinterpret_cast<float4*>(&R3u[r * 136 + c]) = z4;
    }
    for (int i = tid; i < 640; i += 1024) sWc[i] = Wc[i];
    if (tid < 10) sbc[tid] = bc[tid];
    if (tid >= 32 && tid < 64) { sAs[192 + tid] = 0.f; sAd[192 + tid] = 0.f; }  // tails 224..255
    if (tid < NPG) yout[gbase + tid] = (float)y[gbase + tid];   // fused ycopy
    __syncthreads();
    for (int i = tid; i < cnt; i += 1024) {                  // edge multiplicities
        unsigned v = bucket[(size_t)g * CAP + i];
        atomicAdd(&scnt[(v >> 8) * 16 + ((v & 255) >> 3)], 1u << ((v & 7) * 4));
    }
    __syncthreads();

    // ---- layer 1: gemm + agg ----
    gemm_block<128, 136>(R3u, W1T, as1, ad1, sHT, sAs, sAd, lane, wave);
    __syncthreads();

    f32x4 res[2];
    res[0] = (f32x4){0.f, 0.f, 0.f, 0.f};
    res[1] = (f32x4){0.f, 0.f, 0.f, 0.f};
    agg_heads(R3u, sHT, scnt, sAs, sAd, sRZ, res, lane, wave);   // P1 over sX

    // epilogue -> sB (bf16 [112][72] at R3, over dead P1): +b1, relu
    {
        unsigned short* sB = R3u;
        int fr = lane & 15;
#pragma unroll
        for (int i = 0; i < 2; ++i) {
            int t = wave + 16 * i;
            if (t < 28) {
                int mt = t >> 2, nt = t & 3;
                int col = nt * 16 + fr;
                float bv = b1[col];
                int d0 = mt * 16 + (lane >> 4) * 4;
                unsigned u01 = cvt_pk(fmaxf(0.5f * res[i][0] + bv, 0.f),
                                      fmaxf(0.5f * res[i][1] + bv, 0.f));
                unsigned u23 = cvt_pk(fmaxf(0.5f * res[i][2] + bv, 0.f),
                                      fmaxf(0.5f * res[i][3] + bv, 0.f));
                if (d0 + 0 < NPG) sB[(d0 + 0) * 72 + col] = (unsigned short)u01;
                if (d0 + 1 < NPG) sB[(d0 + 1) * 72 + col] = (unsigned short)(u01 >> 16);
                if (d0 + 2 < NPG) sB[(d0 + 2) * 72 + col] = (unsigned short)u23;
                if (d0 + 3 < NPG) sB[(d0 + 3) * 72 + col] = (unsigned short)(u23 >> 16);
            }
        }
        for (int i = tid; i < 12 * 9; i += 1024) {           // zero sB rows 100..111
            int r = 100 + i / 9, c = (i % 9) * 8;
            *reinterpret_cast<float4*>(&sB[r * 72 + c]) = z4;
        }
    }
    __syncthreads();

    // ---- layer 2: gemm + agg ----
    gemm_block<64, 72>(R3u, W2T, as2, ad2, sHT, sAs, sAd, lane, wave);
    __syncthreads();

    res[0] = (f32x4){0.f, 0.f, 0.f, 0.f};
    res[1] = (f32x4){0.f, 0.f, 0.f, 0.f};
    agg_heads(R3u, sHT, scnt, sAs, sAd, sRZ, res, lane, wave);   // P2 over sB

    // epilogue -> sOut (f32 [112][68] over dead sHT): +b2, no relu
    {
        int fr = lane & 15;
#pragma unroll
        for (int i = 0; i < 2; ++i) {
            int t = wave + 16 * i;
            if (t < 28) {
                int mt = t >> 2, nt = t & 3;
                int col = nt * 16 + fr;
                float bv = b2[col];
#pragma unroll
                for (int r = 0; r < 4; ++r) {
                    int d = mt * 16 + (lane >> 4) * 4 + r;
                    if (d < NPG) sOut[d * 68 + col] = 0.5f * res[i][r] + bv;
                }
            }
        }
    }
    __syncthreads();

    // ---- classifier (float4 LDS reads) ----
    for (int idx = tid; idx < NPG * 10; idx += 1024) {
        int d = idx / 10, j = idx % 10;
        float acc = sbc[j];
#pragma unroll
        for (int c = 0; c < 64; c += 4) {
            float4 h4 = *reinterpret_cast<const float4*>(&sOut[d * 68 + c]);
            acc += h4.x * sWc[(c + 0) * 10 + j];
            acc += h4.y * sWc[(c + 1) * 10 + j];
            acc += h4.z * sWc[(c + 2) * 10 + j];
            acc += h4.w * sWc[(c + 3) * 10 + j];
        }
        preds[(size_t)(gbase + d) * 10 + j] = acc;
    }
}

extern "C" void kernel_launch(void* const* d_in, const int* in_sizes, int n_in,
                              void* d_out, int out_size, void* d_ws, size_t ws_size,
                              hipStream_t stream) {
    const float* x   = (const float*)d_in[0];
    const int*   ei  = (const int*)d_in[1];
    const int*   y   = (const int*)d_in[3];
    const float* W1  = (const float*)d_in[4];
    const float* as1 = (const float*)d_in[5];
    const float* ad1 = (const float*)d_in[6];
    const float* b1  = (const float*)d_in[7];
    const float* W2  = (const float*)d_in[8];
    const float* as2 = (const float*)d_in[9];
    const float* ad2 = (const float*)d_in[10];
    const float* b2  = (const float*)d_in[11];
    const float* Wc  = (const float*)d_in[12];
    const float* bc  = (const float*)d_in[13];

    int n = in_sizes[0] / 128;   // 50000
    int e = in_sizes[1] / 2;     // 850000
    int G = n / NPG;             // 500 graphs
    const int* src = ei;
    const int* dst = ei + e;

    char* ws = (char*)d_ws;
    size_t off = 0;
    auto alloc = [&](size_t bytes) -> void* {
        void* p = ws + off;
        off = (off + bytes + 255) & ~size_t(255);
        return p;
    };
    unsigned short* W1T = (unsigned short*)alloc((size_t)128 * 128 * 2);
    unsigned short* W2T = (unsigned short*)alloc((size_t)128 * 64 * 2);
    int* gcnt = (int*)alloc((size_t)G * 4);
    unsigned short* bucket = (unsigned short*)alloc((size_t)G * CAP * 2);

    float* preds = (float*)d_out;
    float* yout  = preds + (size_t)n * 10;

    int bb = (e + EPB - 1) / EPB;

    // prep: weight convert + gcnt zero, then edge bucketing
    convert_w<<<96, 256, 0, stream>>>(W1, W2, W1T, W2T, gcnt, G);
    bucket2_kernel<<<bb, 1024, 0, stream>>>(src, dst, gcnt, bucket, e);

    // the whole network, one block per graph (2 blocks/CU, 32 waves/CU)
    graph_fused<<<G, 1024, SMEM_BYTES, stream>>>(x, W1T, W2T, as1, ad1, b1,
                                                 as2, ad2, b2, Wc, bc,
                                                 gcnt, bucket, y, preds, yout);
}